// Round 9
// baseline (445.162 us; speedup 1.0000x reference)
//
#include <hip/hip_runtime.h>
#include <hip/hip_bf16.h>
#include <hip/hip_fp16.h>

typedef __hip_bfloat16 bf16;
typedef __attribute__((ext_vector_type(8))) short short8;
typedef __attribute__((ext_vector_type(4))) float f32x4;

#define EPS 1e-5f
#define NSLOPE 0.01f
#define NSMAX 3   // max s-slices per q-tile (128-col chunks, <=3 per slice)

__device__ __forceinline__ float b2f(bf16 v) { return __bfloat162float(v); }
__device__ __forceinline__ float bs2f(unsigned short s) {
  bf16 t; __builtin_memcpy(&t, &s, 2); return __bfloat162float(t);
}
__device__ __forceinline__ float ld1(const void* p, size_t idx, int isbf) {
  if (isbf) return b2f(((const bf16*)p)[idx]);
  return ((const float*)p)[idx];
}
__device__ __forceinline__ void st1(void* p, size_t idx, int isbf, float v) {
  if (isbf) ((bf16*)p)[idx] = __float2bfloat16(v);
  else      ((float*)p)[idx] = v;
}
__device__ __forceinline__ short f2bs(float x) {
  bf16 t = __float2bfloat16(x);
  short s; __builtin_memcpy(&s, &t, 2); return s;
}
// pack 8 consecutive floats -> short8 of bf16
__device__ __forceinline__ short8 pack8f(const float* p) {
  float4 a = *(const float4*)p, b = *(const float4*)(p + 4);
  short8 r;
  r[0] = f2bs(a.x); r[1] = f2bs(a.y); r[2] = f2bs(a.z); r[3] = f2bs(a.w);
  r[4] = f2bs(b.x); r[5] = f2bs(b.y); r[6] = f2bs(b.z); r[7] = f2bs(b.w);
  return r;
}
// pack two already-loaded float4s (as uint4 raws) -> short8 of bf16
__device__ __forceinline__ short8 pack8u(uint4 a, uint4 b) {
  const float* fa = (const float*)&a;
  const float* fb = (const float*)&b;
  short8 r;
  r[0] = f2bs(fa[0]); r[1] = f2bs(fa[1]); r[2] = f2bs(fa[2]); r[3] = f2bs(fa[3]);
  r[4] = f2bs(fb[0]); r[5] = f2bs(fb[1]); r[6] = f2bs(fb[2]); r[7] = f2bs(fb[3]);
  return r;
}

// ---------------------------------------------------------------------------
// K0: meta (row_start, len per batch) + dtype sniffer + W1 -> bf16 convert
// + FUSED stat branch (x_stat_out) in blocks 0..B-1.
// ---------------------------------------------------------------------------
__global__ void meta_kernel(const void* __restrict__ xt,
                            const int* __restrict__ bidx, const int* __restrict__ pidx,
                            int N, int B, int* __restrict__ rs, int* __restrict__ ln,
                            int* __restrict__ flag,
                            const void* __restrict__ W1, bf16* __restrict__ w1b, int w1n,
                            const void* __restrict__ xstat, const void* __restrict__ W2,
                            const void* __restrict__ b2, const void* __restrict__ g2,
                            const void* __restrict__ be2, const void* __restrict__ mn2,
                            const void* __restrict__ vr2, void* __restrict__ out,
                            long long obase) {
  int isbf_l = 0;
  {
    unsigned w = ((const unsigned*)xt)[threadIdx.x & 63];
    unsigned lo = w & 0xffffu;
    unsigned ex = (lo >> 7) & 0xffu;
    bool sane = ((lo & 0x7fffu) == 0u) || (ex >= 96u && ex <= 134u);
    unsigned long long m = __ballot(sane);
    isbf_l = (__popcll(m) >= 48) ? 1 : 0;
    if (blockIdx.x == 0 && threadIdx.x == 0) flag[0] = isbf_l;
  }
  int stride = gridDim.x * blockDim.x;
  int g0 = blockIdx.x * blockDim.x + threadIdx.x;
  for (int i = g0; i < N; i += stride) {
    int b = bidx[i];
    if ((unsigned)b >= (unsigned)B) continue;
    if (i == 0 || bidx[i - 1] != b) rs[b] = i;
    if (i == N - 1 || bidx[i + 1] != b) ln[b] = pidx[i] + 1;
  }
  for (int i = g0; i < w1n; i += stride) {
    int o = i / 192, k = i - o * 192;          // W1[o][k], o<128, k<192
    int ct = o >> 4, n = o & 15;
    int ks = k >> 5, rem = k & 31;
    int q = rem >> 3, j = rem & 7;
    int fi = ((ct * 6 + ks) * 64 + q * 16 + n) * 8 + j;
    w1b[fi] = __float2bfloat16(ld1(W1, i, isbf_l));
  }
  // ---- fused stat: x_stat_out = leaky(bn2(x_stat @ W2^T + b2)) ----
  __shared__ float xs[64];
  if (threadIdx.x < 64 && blockIdx.x < B)
    xs[threadIdx.x] = ld1(xstat, blockIdx.x * 64 + threadIdx.x, isbf_l);
  __syncthreads();
  if (threadIdx.x < 64 && blockIdx.x < B) {
    const int o = threadIdx.x, bb = blockIdx.x;
    float acc = ld1(b2, o, isbf_l);
#pragma unroll 8
    for (int j = 0; j < 64; ++j) acc += xs[j] * ld1(W2, o * 64 + j, isbf_l);
    float k1 = ld1(g2, o, isbf_l) * rsqrtf(ld1(vr2, o, isbf_l) + EPS);
    float k0 = ld1(be2, o, isbf_l) - ld1(mn2, o, isbf_l) * k1;
    float v = acc * k1 + k0;
    v = (v >= 0.f) ? v : NSLOPE * v;
    st1(out, (size_t)(obase + bb * 64 + o), isbf_l, v);
  }
}

// ---------------------------------------------------------------------------
// Kf: flag-aware zero fill of x_out (fallback when ws too small)
// ---------------------------------------------------------------------------
__global__ void zfill_kernel(void* out, const int* __restrict__ flag, long long n) {
  const int isbf = flag[0];
  long long i = (long long)blockIdx.x * blockDim.x + threadIdx.x;
  long long stride = (long long)gridDim.x * blockDim.x;
  for (; i < n; i += stride) st1(out, (size_t)i, isbf, 0.f);
}

// ---------------------------------------------------------------------------
// K1: h = leaky(bn1(concat(x_temp, x_stat[bidx]) @ W1^T + b1))  via MFMA.
// ---------------------------------------------------------------------------
__global__ __launch_bounds__(256) void h_mfma_kernel(
    const void* __restrict__ xt, const void* __restrict__ xsg,
    const int* __restrict__ bidx, const bf16* __restrict__ w1b,
    const void* __restrict__ b1,
    const void* __restrict__ g1, const void* __restrict__ be1,
    const void* __restrict__ mn1, const void* __restrict__ vr1,
    const int* __restrict__ flag, bf16* __restrict__ hout, int N) {
  const int isbf = flag[0];
  const int tid = threadIdx.x, lane = tid & 63, wv = tid >> 6;
  const int m16 = lane & 15, quad = lane >> 4;
  const int row0 = blockIdx.x * 64 + wv * 16;
  const int m = row0 + m16;
  const int mc = (m < N) ? m : (N - 1);
  const int bi = bidx[mc];

  short8 af[6];
  if (isbf) {
    const bf16* xr = (const bf16*)xt + (size_t)mc * 128 + quad * 8;
#pragma unroll
    for (int ks = 0; ks < 4; ++ks) af[ks] = *(const short8*)(xr + ks * 32);
    const bf16* sr = (const bf16*)xsg + (size_t)bi * 64 + quad * 8;
    af[4] = *(const short8*)sr;
    af[5] = *(const short8*)(sr + 32);
  } else {
    const float* xr = (const float*)xt + (size_t)mc * 128 + quad * 8;
#pragma unroll
    for (int ks = 0; ks < 4; ++ks) af[ks] = pack8f(xr + ks * 32);
    const float* sr = (const float*)xsg + (size_t)bi * 64 + quad * 8;
    af[4] = pack8f(sr);
    af[5] = pack8f(sr + 32);
  }

  f32x4 acc[8];
#pragma unroll
  for (int ct = 0; ct < 8; ++ct) acc[ct] = (f32x4){0.f, 0.f, 0.f, 0.f};

  const short8* wf = (const short8*)w1b;   // fragment-ordered (see meta)
#pragma unroll
  for (int ks = 0; ks < 6; ++ks) {
#pragma unroll
    for (int ct = 0; ct < 8; ++ct) {
      short8 bfrag = wf[(ct * 6 + ks) * 64 + lane];
      acc[ct] = __builtin_amdgcn_mfma_f32_16x16x32_bf16(af[ks], bfrag, acc[ct], 0, 0, 0);
    }
  }

#pragma unroll
  for (int ct = 0; ct < 8; ++ct) {
    const int o = ct * 16 + m16;
    float k1 = ld1(g1, o, isbf) * rsqrtf(ld1(vr1, o, isbf) + EPS);
    float k0 = ld1(be1, o, isbf) - ld1(mn1, o, isbf) * k1;
    float bias = ld1(b1, o, isbf);
#pragma unroll
    for (int r = 0; r < 4; ++r) {
      int mr = row0 + quad * 4 + r;
      if (mr < N) {
        float v = (acc[ct][r] + bias) * k1 + k0;
        v = (v >= 0.f) ? v : NSLOPE * v;
        hout[(size_t)mr * 128 + o] = __float2bfloat16(v);
      }
    }
  }
}

// ---------------------------------------------------------------------------
// K3a: split-s partial attention, WIDE 128-column chunks.
// r7/r8 proved attn time is invariant to block count, LDS size, and grid
// shape: ~19k cycles per 64-col chunk vs ~2k of work, with 1 wave/SIMD.
// Remaining lever: amortize the per-chunk serial chain. Body now covers
// 128 s-cols: ONE barrier pair per 128 cols (was 2), ONE softmax pass
// (was 2), and 32 K-loads + 8 V-staging + ta loads all in flight together
// (2x MLP). vT/Pw are split into two 64-col halves with the proven
// stride-72 layout (identical bank behavior to r8).
// ---------------------------------------------------------------------------
__global__ __launch_bounds__(256, 2) void attn_part_kernel(
    const void* __restrict__ ta, const bf16* __restrict__ h,
    const int* __restrict__ rs_arr, const int* __restrict__ ln_arr,
    const int* __restrict__ flag,
    unsigned short* __restrict__ accp_buf, unsigned short* __restrict__ acct_buf,
    float* __restrict__ ms_buf, float* __restrict__ ls_buf,
    int T, int N, int TT) {
  __shared__ __align__(16) unsigned short vT[2][128][72];    // 36864 B
  __shared__ __align__(16) unsigned short Pw[4][16][2][72];  // 18432 B

  const int b = blockIdx.y;
  const int tt = blockIdx.x / NSMAX, sl = blockIdx.x % NSMAX;
  const int t0 = tt * 64;
  const int len = ln_arr[b];
  if (t0 >= len) return;               // uniform exit before any barrier
  const int nchunk = (len + 127) >> 7; // 128-col chunks
  const int ns = (nchunk + 2) / 3;     // slices for this batch (<= NSMAX)
  if (sl >= ns) return;                // uniform
  const int c_begin = (sl * nchunk) / ns;
  const int c_end = ((sl + 1) * nchunk) / ns;

  const int isbf = flag[0];
  const int rs = rs_arr[b];
  const int tid = threadIdx.x;
  const int lane = tid & 63, wv = tid >> 6;
  const int m16 = lane & 15, quad = lane >> 4;
  const int t0w = t0 + wv * 16;        // this wave's 16 query rows

  // ---- Q fragments: A[m=t][k=c], m=lane&15, k=quad*8+j (+32*ks) ----
  short8 qf[4];
  {
    int qrow = rs + t0w + m16;
    if (qrow > N - 1) qrow = N - 1;    // clamp: rows t>=len are never merged
    const bf16* qp = h + (size_t)qrow * 128 + quad * 8;
#pragma unroll
    for (int ks = 0; ks < 4; ++ks) qf[ks] = *(const short8*)(qp + ks * 32);
  }

  const float scale = 0.08838834764831845f;  // 1/sqrt(128)
  const short8 zero8 = {0, 0, 0, 0, 0, 0, 0, 0};
  const uint4 zz = {0, 0, 0, 0};
  const size_t tarow = ((size_t)b * T + (t0w + m16)) * (size_t)T;
  const int c8base = wv * 32;          // this wave stages channels c8base..+31

  f32x4 accp[8], acct[8];
#pragma unroll
  for (int ct = 0; ct < 8; ++ct) {
    accp[ct] = (f32x4){0.f, 0.f, 0.f, 0.f};
    acct[ct] = (f32x4){0.f, 0.f, 0.f, 0.f};
  }
  float mrun[4], lrun[4];
#pragma unroll
  for (int r = 0; r < 4; ++r) { mrun[r] = -INFINITY; lrun[r] = 0.f; }

  // ---- prologue: stage chunk c_begin (both 64-col halves) into vT ----
  {
    const int s0 = c_begin << 7;
#pragma unroll
    for (int hf = 0; hf < 2; ++hf) {
      int srow = s0 + hf * 64 + lane;
      bool v = srow < len;
      const bf16* src = h + (size_t)(rs + (v ? srow : 0)) * 128;
#pragma unroll
      for (int it = 0; it < 4; ++it) {
        int c8 = c8base + it * 8;
        uint4 u = v ? *(const uint4*)(src + c8) : zz;
        const unsigned short* a = (const unsigned short*)&u;
#pragma unroll
        for (int j = 0; j < 8; ++j) vT[hf][c8 + j][lane] = a[j];
      }
    }
  }
  __syncthreads();

  for (int ci = c_begin; ci < c_end; ++ci) {
    const int s0 = ci << 7;
    const bool have_next = (ci + 1 < c_end);   // block-uniform

    // ---- issue next chunk's V loads NOW; they land during compute ----
    uint4 su[2][4];
#pragma unroll
    for (int hf = 0; hf < 2; ++hf) {
#pragma unroll
      for (int it = 0; it < 4; ++it) su[hf][it] = zz;
    }
    if (have_next) {
#pragma unroll
      for (int hf = 0; hf < 2; ++hf) {
        int srow = s0 + 128 + hf * 64 + lane;
        bool v = srow < len;
        const bf16* src = h + (size_t)(rs + (v ? srow : 0)) * 128;
        if (v) {
#pragma unroll
          for (int it = 0; it < 4; ++it)
            su[hf][it] = *(const uint4*)(src + c8base + it * 8);
        }
      }
    }

    // ---- temp_attn A-frags for all 128 cols of this chunk ----
    short8 taf[4];
    if (isbf) {
      const bf16* tp = (const bf16*)ta + tarow + s0 + quad * 8;
#pragma unroll
      for (int ks = 0; ks < 4; ++ks) taf[ks] = *(const short8*)(tp + ks * 32);
    } else {
      const float* tp = (const float*)ta + tarow + s0 + quad * 8;
#pragma unroll
      for (int ks = 0; ks < 4; ++ks) {
        uint4 ua = *(const uint4*)(tp + ks * 32);
        uint4 ub = *(const uint4*)(tp + ks * 32 + 4);
        taf[ks] = pack8u(ua, ub);
      }
    }

    // ---- QK over 128 cols: S[t=quad*4+r][s=st*16+m16], st=0..7 ----
    f32x4 sa[8];
    bool sval[8];
#pragma unroll
    for (int st = 0; st < 8; ++st) {
      int srow = s0 + st * 16 + m16;
      bool v = srow < len;
      sval[st] = v;
      const bf16* kp = h + (size_t)(rs + (v ? srow : 0)) * 128 + quad * 8;
      f32x4 a0 = (f32x4){0.f, 0.f, 0.f, 0.f};
#pragma unroll
      for (int ks = 0; ks < 4; ++ks) {
        short8 kf = v ? *(const short8*)(kp + ks * 32) : zero8;
        a0 = __builtin_amdgcn_mfma_f32_16x16x32_bf16(qf[ks], kf, a0, 0, 0, 0);
      }
      sa[st] = a0;
    }

    // ---- single in-wave online softmax pass over 128 cols ----
    float cm[4];
#pragma unroll
    for (int r = 0; r < 4; ++r) cm[r] = -INFINITY;
#pragma unroll
    for (int st = 0; st < 8; ++st) {
#pragma unroll
      for (int r = 0; r < 4; ++r)
        cm[r] = fmaxf(cm[r], sval[st] ? sa[st][r] * scale : -INFINITY);
    }
#pragma unroll
    for (int off = 1; off <= 8; off <<= 1) {
#pragma unroll
      for (int r = 0; r < 4; ++r) cm[r] = fmaxf(cm[r], __shfl_xor(cm[r], off, 64));
    }
    float al[4], csum[4];
#pragma unroll
    for (int r = 0; r < 4; ++r) {
      float mnew = fmaxf(mrun[r], cm[r]);   // finite: col c_begin*128 valid
      al[r] = __expf(mrun[r] - mnew);       // 0 on first chunk
      mrun[r] = mnew;
      csum[r] = 0.f;
    }
#pragma unroll
    for (int st = 0; st < 8; ++st) {
#pragma unroll
      for (int r = 0; r < 4; ++r) {
        float pv = sval[st] ? __expf(sa[st][r] * scale - mrun[r]) : 0.f;
        csum[r] += pv;
        Pw[wv][quad * 4 + r][st >> 2][(st & 3) * 16 + m16] = (unsigned short)f2bs(pv);
      }
    }
#pragma unroll
    for (int off = 1; off <= 8; off <<= 1) {
#pragma unroll
      for (int r = 0; r < 4; ++r) csum[r] += __shfl_xor(csum[r], off, 64);
    }
#pragma unroll
    for (int r = 0; r < 4; ++r) lrun[r] = lrun[r] * al[r] + csum[r];

    // rescale P-accumulator by alpha (ta-acc is linear, untouched)
#pragma unroll
    for (int ct = 0; ct < 8; ++ct) {
#pragma unroll
      for (int r = 0; r < 4; ++r) accp[ct][r] *= al[r];
    }

    // ---- PV + taV over 128 cols: ks 0..3 (half = ks>>1) ----
#pragma unroll
    for (int ks = 0; ks < 4; ++ks) {
      short8 pf = *(const short8*)&Pw[wv][m16][ks >> 1][(ks & 1) * 32 + quad * 8];
      short8 tf = taf[ks];
#pragma unroll
      for (int ct = 0; ct < 8; ++ct) {
        short8 bfv = *(const short8*)&vT[ks >> 1][ct * 16 + m16][(ks & 1) * 32 + quad * 8];
        accp[ct] = __builtin_amdgcn_mfma_f32_16x16x32_bf16(pf, bfv, accp[ct], 0, 0, 0);
        acct[ct] = __builtin_amdgcn_mfma_f32_16x16x32_bf16(tf, bfv, acct[ct], 0, 0, 0);
      }
    }

    // ---- single-buffer rotate: wait readers, overwrite, publish ----
    if (have_next) {
      __syncthreads();   // all waves done reading vT for chunk ci
#pragma unroll
      for (int hf = 0; hf < 2; ++hf) {
#pragma unroll
        for (int it = 0; it < 4; ++it) {
          const unsigned short* a = (const unsigned short*)&su[hf][it];
#pragma unroll
          for (int j = 0; j < 8; ++j)
            vT[hf][c8base + it * 8 + j][lane] = a[j];
        }
      }
      __syncthreads();   // vT(ci+1) visible to all waves
    }
  }

  // ---- epilogue: write unnormalized partials ----
  const int slot = (b * TT + tt) * NSMAX + sl;
  const size_t abase = (size_t)slot * 8192;   // 64 rows x 128 ch
#pragma unroll
  for (int r = 0; r < 4; ++r) {
    const int row = wv * 16 + quad * 4 + r;
#pragma unroll
    for (int ct = 0; ct < 8; ++ct) {
      const size_t o = abase + (size_t)row * 128 + ct * 16 + m16;
      accp_buf[o] = (unsigned short)f2bs(accp[ct][r]);
      acct_buf[o] = (unsigned short)f2bs(acct[ct][r]);
    }
    if (m16 == 0) {
      ms_buf[(size_t)slot * 64 + row] = mrun[r];
      ls_buf[(size_t)slot * 64 + row] = lrun[r];
    }
  }
}

// ---------------------------------------------------------------------------
// K3b: reducer — merge <=NSMAX slice partials per q-tile, apply analytic
// zero-pad term, normalize, add ta part, write x_out.
// ---------------------------------------------------------------------------
__global__ __launch_bounds__(256) void attn_red_kernel(
    const unsigned short* __restrict__ accp_buf,
    const unsigned short* __restrict__ acct_buf,
    const float* __restrict__ ms_buf, const float* __restrict__ ls_buf,
    const int* __restrict__ rs_arr, const int* __restrict__ ln_arr,
    const int* __restrict__ flag, void* __restrict__ xout, int T, int TT) {
  const int b = blockIdx.y, tt = blockIdx.x, t0 = tt * 64;
  const int len = ln_arr[b];
  if (t0 >= len) return;
  const int isbf = flag[0];
  const int rs = rs_arr[b];
  const int nchunk = (len + 127) >> 7;       // 128-col chunks (match K3a!)
  const int ns = (nchunk + 2) / 3;
  const int base_slot = (b * TT + tt) * NSMAX;

  const int r = threadIdx.x >> 2;            // row 0..63
  const int cg = threadIdx.x & 3;            // col group (32 cols)
  const int trow = t0 + r;
  if (trow >= len) return;

  // ---- stats merge ----
  float m0 = ms_buf[(size_t)(base_slot + 0) * 64 + r];
  float m1 = (ns > 1) ? ms_buf[(size_t)(base_slot + 1) * 64 + r] : -INFINITY;
  float m2 = (ns > 2) ? ms_buf[(size_t)(base_slot + 2) * 64 + r] : -INFINITY;
  float M = fmaxf(m0, fmaxf(m1, m2));
  float w0 = __expf(m0 - M);
  float w1 = (ns > 1) ? __expf(m1 - M) : 0.f;
  float w2 = (ns > 2) ? __expf(m2 - M) : 0.f;
  float L = ls_buf[(size_t)(base_slot + 0) * 64 + r] * w0;
  if (ns > 1) L += ls_buf[(size_t)(base_slot + 1) * 64 + r] * w1;
  if (ns > 2) L += ls_buf[(size_t)(base_slot + 2) * 64 + r] * w2;

  float m_f = (len < T) ? fmaxf(M, 0.f) : M;
  float corr = __expf(M - m_f);
  float l_f = L * corr + (float)(T - len) * __expf(-m_f);
  float os = corr / l_f;

  const size_t p0 = (size_t)(base_slot + 0) * 8192 + (size_t)r * 128 + cg * 32;
  const size_t p1 = (size_t)(base_slot + 1) * 8192 + (size_t)r * 128 + cg * 32;
  const size_t p2 = (size_t)(base_slot + 2) * 8192 + (size_t)r * 128 + cg * 32;
  const size_t ob = (size_t)(rs + trow) * 128 + cg * 32;

#pragma unroll
  for (int g = 0; g < 4; ++g) {
    float acc[8], tac[8];
    {
      short8 ap = *(const short8*)&accp_buf[p0 + g * 8];
      short8 at = *(const short8*)&acct_buf[p0 + g * 8];
#pragma unroll
      for (int j = 0; j < 8; ++j) {
        acc[j] = bs2f((unsigned short)ap[j]) * w0;
        tac[j] = bs2f((unsigned short)at[j]);
      }
    }
    if (ns > 1) {
      short8 ap = *(const short8*)&accp_buf[p1 + g * 8];
      short8 at = *(const short8*)&acct_buf[p1 + g * 8];
#pragma unroll
      for (int j = 0; j < 8; ++j) {
        acc[j] += bs2f((unsigned short)ap[j]) * w1;
        tac[j] += bs2f((unsigned short)at[j]);
      }
    }
    if (ns > 2) {
      short8 ap = *(const short8*)&accp_buf[p2 + g * 8];
      short8 at = *(const short8*)&acct_buf[p2 + g * 8];
#pragma unroll
      for (int j = 0; j < 8; ++j) {
        acc[j] += bs2f((unsigned short)ap[j]) * w2;
        tac[j] += bs2f((unsigned short)at[j]);
      }
    }
#pragma unroll
    for (int j = 0; j < 8; ++j)
      st1(xout, ob + g * 8 + j, isbf, acc[j] * os + tac[j]);
  }
}

// ---------------------------------------------------------------------------
// K3 (fallback): single-pass attention (r2 kernel, best verified single-pass)
// ---------------------------------------------------------------------------
__global__ __launch_bounds__(256, 2) void attn_mfma_kernel(
    const void* __restrict__ ta, const bf16* __restrict__ h,
    const int* __restrict__ rs_arr, const int* __restrict__ ln_arr,
    const int* __restrict__ flag, void* __restrict__ xout, int T, int N) {
  __shared__ __align__(16) unsigned short vT[2][128][72];
  __shared__ __align__(16) unsigned short Pw[4][16][72];

  const int b = blockIdx.y, t0 = blockIdx.x * 64;
  const int len = ln_arr[b];
  if (t0 >= len) return;
  const int isbf = flag[0];
  const int rs = rs_arr[b];
  const int tid = threadIdx.x;
  const int lane = tid & 63, wv = tid >> 6;
  const int m16 = lane & 15, quad = lane >> 4;
  const int t0w = t0 + wv * 16;

  short8 qf[4];
  {
    int qrow = rs + t0w + m16;
    if (qrow > N - 1) qrow = N - 1;
    const bf16* qp = h + (size_t)qrow * 128 + quad * 8;
#pragma unroll
    for (int ks = 0; ks < 4; ++ks) qf[ks] = *(const short8*)(qp + ks * 32);
  }

  const float scale = 0.08838834764831845f;
  const short8 zero8 = {0, 0, 0, 0, 0, 0, 0, 0};
  const uint4 zz = {0, 0, 0, 0};
  const size_t tarow = ((size_t)b * T + (t0w + m16)) * (size_t)T;
  const int c8base = wv * 32;

  f32x4 accp[8], acct[8];
#pragma unroll
  for (int ct = 0; ct < 8; ++ct) {
    accp[ct] = (f32x4){0.f, 0.f, 0.f, 0.f};
    acct[ct] = (f32x4){0.f, 0.f, 0.f, 0.f};
  }
  float mrun[4], lrun[4];
#pragma unroll
  for (int r = 0; r < 4; ++r) { mrun[r] = -INFINITY; lrun[r] = 0.f; }

  {
    int srow = lane;
    bool v = srow < len;
    const bf16* src = h + (size_t)(rs + (v ? srow : 0)) * 128;
#pragma unroll
    for (int it = 0; it < 4; ++it) {
      int c8 = c8base + it * 8;
      uint4 u = v ? *(const uint4*)(src + c8) : zz;
      const unsigned short* a = (const unsigned short*)&u;
#pragma unroll
      for (int j = 0; j < 8; ++j) vT[0][c8 + j][lane] = a[j];
    }
  }
  __syncthreads();

  const int nchunk = (len + 63) >> 6;
  for (int ci = 0; ci < nchunk; ++ci) {
    const int s0 = ci << 6;
    const int p = ci & 1;
    const bool have_next = (ci + 1 < nchunk);

    uint4 su0 = zz, su1 = zz, su2 = zz, su3 = zz;
    if (have_next) {
      int srow = s0 + 64 + lane;
      bool v = srow < len;
      const bf16* src = h + (size_t)(rs + (v ? srow : 0)) * 128;
      if (v) {
        su0 = *(const uint4*)(src + c8base);
        su1 = *(const uint4*)(src + c8base + 8);
        su2 = *(const uint4*)(src + c8base + 16);
        su3 = *(const uint4*)(src + c8base + 24);
      }
    }

    short8 taf0, taf1;
    if (isbf) {
      const bf16* tp = (const bf16*)ta + tarow + s0 + quad * 8;
      taf0 = *(const short8*)tp;
      taf1 = *(const short8*)(tp + 32);
    } else {
      const float* tp = (const float*)ta + tarow + s0 + quad * 8;
      taf0 = pack8f(tp);
      taf1 = pack8f(tp + 32);
    }

    f32x4 sa[4];
    bool sval[4];
#pragma unroll
    for (int st = 0; st < 4; ++st) {
      int srow = s0 + st * 16 + m16;
      bool v = srow < len;
      sval[st] = v;
      const bf16* kp = h + (size_t)(rs + (v ? srow : 0)) * 128 + quad * 8;
      f32x4 a0 = (f32x4){0.f, 0.f, 0.f, 0.f};
#pragma unroll
      for (int ks = 0; ks < 4; ++ks) {
        short8 kf = v ? *(const short8*)(kp + ks * 32) : zero8;
        a0 = __builtin_amdgcn_mfma_f32_16x16x32_bf16(qf[ks], kf, a0, 0, 0, 0);
      }
      sa[st] = a0;
    }

    float cm[4];
#pragma unroll
    for (int r = 0; r < 4; ++r) cm[r] = -INFINITY;
#pragma unroll
    for (int st = 0; st < 4; ++st) {
#pragma unroll
      for (int r = 0; r < 4; ++r)
        cm[r] = fmaxf(cm[r], sval[st] ? sa[st][r] * scale : -INFINITY);
    }
#pragma unroll
    for (int off = 1; off <= 8; off <<= 1) {
#pragma unroll
      for (int r = 0; r < 4; ++r) cm[r] = fmaxf(cm[r], __shfl_xor(cm[r], off, 64));
    }
    float al[4], csum[4];
#pragma unroll
    for (int r = 0; r < 4; ++r) {
      float mnew = fmaxf(mrun[r], cm[r]);
      al[r] = __expf(mrun[r] - mnew);
      mrun[r] = mnew;
      csum[r] = 0.f;
    }
#pragma unroll
    for (int st = 0; st < 4; ++st) {
#pragma unroll
      for (int r = 0; r < 4; ++r) {
        float pv = sval[st] ? __expf(sa[st][r] * scale - mrun[r]) : 0.f;
        csum[r] += pv;
        Pw[wv][quad * 4 + r][st * 16 + m16] = (unsigned short)f2bs(pv);
      }
    }
#pragma unroll
    for (int off = 1; off <= 8; off <<= 1) {
#pragma unroll
      for (int r = 0; r < 4; ++r) csum[r] += __shfl_xor(csum[r], off, 64);
    }
#pragma unroll
    for (int r = 0; r < 4; ++r) lrun[r] = lrun[r] * al[r] + csum[r];

#pragma unroll
    for (int ct = 0; ct < 8; ++ct) {
#pragma unroll
      for (int r = 0; r < 4; ++r) accp[ct][r] *= al[r];
    }

#pragma unroll
    for (int ks = 0; ks < 2; ++ks) {
      short8 pf = *(const short8*)&Pw[wv][m16][ks * 32 + quad * 8];
      short8 tf = ks ? taf1 : taf0;
#pragma unroll
      for (int ct = 0; ct < 8; ++ct) {
        short8 bfv = *(const short8*)&vT[p][ct * 16 + m16][ks * 32 + quad * 8];
        accp[ct] = __builtin_amdgcn_mfma_f32_16x16x32_bf16(pf, bfv, accp[ct], 0, 0, 0);
        acct[ct] = __builtin_amdgcn_mfma_f32_16x16x32_bf16(tf, bfv, acct[ct], 0, 0, 0);
      }
    }

    if (have_next) {
      const unsigned short* a0 = (const unsigned short*)&su0;
      const unsigned short* a1 = (const unsigned short*)&su1;
      const unsigned short* a2 = (const unsigned short*)&su2;
      const unsigned short* a3 = (const unsigned short*)&su3;
#pragma unroll
      for (int j = 0; j < 8; ++j) {
        vT[p ^ 1][c8base + j][lane]      = a0[j];
        vT[p ^ 1][c8base + 8 + j][lane]  = a1[j];
        vT[p ^ 1][c8base + 16 + j][lane] = a2[j];
        vT[p ^ 1][c8base + 24 + j][lane] = a3[j];
      }
    }
    __syncthreads();
  }

  const int nr = len - t0w;
#pragma unroll
  for (int r = 0; r < 4; ++r) {
    int t = quad * 4 + r;
    if (t < nr) {
      float m_r = mrun[r], l_r = lrun[r];
      float m_f = (len < T) ? fmaxf(m_r, 0.f) : m_r;
      float corr = __expf(m_r - m_f);
      float l_f = l_r * corr + (float)(T - len) * __expf(-m_f);
      float os = corr / l_f;
      size_t ob = (size_t)(rs + t0w + t) * 128;
#pragma unroll
      for (int ct = 0; ct < 8; ++ct)
        st1(xout, ob + ct * 16 + m16, isbf, accp[ct][r] * os + acct[ct][r]);
    }
  }
}

// ---------------------------------------------------------------------------
extern "C" void kernel_launch(void* const* d_in, const int* in_sizes, int n_in,
                              void* d_out, int out_size, void* d_ws, size_t ws_size,
                              hipStream_t stream) {
  const void* x_temp    = d_in[0];
  const void* x_stat    = d_in[1];
  const void* temp_attn = d_in[2];
  const int N = in_sizes[0] / 128;      // 23450
  const int B = in_sizes[1] / 64;       // 32
  long long tt = (long long)in_sizes[2] / B;
  int T = 1; while ((long long)(T + 1) * (T + 1) <= tt) ++T;  // isqrt -> 1024
  const int TT = (T + 63) >> 6;         // q-tiles per batch (16)

  int p = 3;
  while (p < n_in && in_sizes[p] != N) ++p;
  const int* batch_idx = (const int*)d_in[p++];
  const int* pos_idx   = (const int*)d_in[p++];
  const void* W1 = d_in[p++];
  const void* b1 = d_in[p++];
  const void* g1 = d_in[p++];
  const void* be1= d_in[p++];
  const void* mn1= d_in[p++];
  const void* vr1= d_in[p++];
  const void* W2 = d_in[p++];
  const void* b2 = d_in[p++];
  const void* g2 = d_in[p++];
  const void* be2= d_in[p++];
  const void* mn2= d_in[p++];
  const void* vr2= d_in[p++];

  int*  meta = (int*)d_ws;
  int*  rs   = meta;
  int*  lnp  = meta + B;
  int*  flag = meta + 2 * B;
  size_t off = 1024;
  bf16* h    = (bf16*)((char*)d_ws + off);  off += (size_t)N * 128 * 2;
  const int w1n = 128 * 192;
  bf16* w1b  = (bf16*)((char*)d_ws + off);  off += (size_t)w1n * 2;
  off = (off + 255) & ~(size_t)255;
  size_t need_min = off;
  const size_t nslot = (size_t)B * TT * NSMAX;
  unsigned short* accp_buf = (unsigned short*)((char*)d_ws + off);
  off += nslot * 8192 * 2;
  unsigned short* acct_buf = (unsigned short*)((char*)d_ws + off);
  off += nslot * 8192 * 2;
  float* ms_buf = (float*)((char*)d_ws + off);  off += nslot * 64 * 4;
  float* ls_buf = (float*)((char*)d_ws + off);  off += nslot * 64 * 4;
  size_t need_split = off;

  long long obase = (long long)N * 128;

  meta_kernel<<<90, 256, 0, stream>>>(x_temp, batch_idx, pos_idx, N, B, rs, lnp,
                                      flag, W1, w1b, w1n,
                                      x_stat, W2, b2, g2, be2, mn2, vr2,
                                      d_out, obase);
  if (ws_size >= need_min) {
    h_mfma_kernel<<<(N + 63) / 64, 256, 0, stream>>>(x_temp, x_stat, batch_idx,
                                                     w1b, b1, g1, be1, mn1, vr1,
                                                     flag, h, N);
    if (ws_size >= need_split) {
      attn_part_kernel<<<dim3(TT * NSMAX, B), 256, 0, stream>>>(
          temp_attn, h, rs, lnp, flag, accp_buf, acct_buf, ms_buf, ls_buf,
          T, N, TT);
      attn_red_kernel<<<dim3(TT, B), 256, 0, stream>>>(
          accp_buf, acct_buf, ms_buf, ls_buf, rs, lnp, flag, d_out, T, TT);
    } else {
      attn_mfma_kernel<<<dim3(TT, B), 256, 0, stream>>>(
          temp_attn, h, rs, lnp, flag, d_out, T, N);
    }
  } else {
    zfill_kernel<<<512, 256, 0, stream>>>(d_out, flag, obase);
  }
}

// Round 10
// 415.315 us; speedup vs baseline: 1.0719x; 1.0719x over previous
//
#include <hip/hip_runtime.h>
#include <hip/hip_bf16.h>
#include <hip/hip_fp16.h>

typedef __hip_bfloat16 bf16;
typedef __attribute__((ext_vector_type(8))) short short8;
typedef __attribute__((ext_vector_type(4))) float f32x4;

#define EPS 1e-5f
#define NSLOPE 0.01f

__device__ __forceinline__ float b2f(bf16 v) { return __bfloat162float(v); }
__device__ __forceinline__ float ld1(const void* p, size_t idx, int isbf) {
  if (isbf) return b2f(((const bf16*)p)[idx]);
  return ((const float*)p)[idx];
}
__device__ __forceinline__ void st1(void* p, size_t idx, int isbf, float v) {
  if (isbf) ((bf16*)p)[idx] = __float2bfloat16(v);
  else      ((float*)p)[idx] = v;
}
__device__ __forceinline__ short f2bs(float x) {
  bf16 t = __float2bfloat16(x);
  short s; __builtin_memcpy(&s, &t, 2); return s;
}
// pack 8 consecutive floats -> short8 of bf16
__device__ __forceinline__ short8 pack8f(const float* p) {
  float4 a = *(const float4*)p, b = *(const float4*)(p + 4);
  short8 r;
  r[0] = f2bs(a.x); r[1] = f2bs(a.y); r[2] = f2bs(a.z); r[3] = f2bs(a.w);
  r[4] = f2bs(b.x); r[5] = f2bs(b.y); r[6] = f2bs(b.z); r[7] = f2bs(b.w);
  return r;
}

// ---------------------------------------------------------------------------
// K0: meta (row_start, len per batch) + dtype sniffer + W1 -> bf16 convert
// + FUSED stat branch (x_stat_out) in blocks 0..B-1.
// ---------------------------------------------------------------------------
__global__ void meta_kernel(const void* __restrict__ xt,
                            const int* __restrict__ bidx, const int* __restrict__ pidx,
                            int N, int B, int* __restrict__ rs, int* __restrict__ ln,
                            int* __restrict__ flag,
                            const void* __restrict__ W1, bf16* __restrict__ w1b, int w1n,
                            const void* __restrict__ xstat, const void* __restrict__ W2,
                            const void* __restrict__ b2, const void* __restrict__ g2,
                            const void* __restrict__ be2, const void* __restrict__ mn2,
                            const void* __restrict__ vr2, void* __restrict__ out,
                            long long obase) {
  int isbf_l = 0;
  {
    unsigned w = ((const unsigned*)xt)[threadIdx.x & 63];
    unsigned lo = w & 0xffffu;
    unsigned ex = (lo >> 7) & 0xffu;
    bool sane = ((lo & 0x7fffu) == 0u) || (ex >= 96u && ex <= 134u);
    unsigned long long m = __ballot(sane);
    isbf_l = (__popcll(m) >= 48) ? 1 : 0;
    if (blockIdx.x == 0 && threadIdx.x == 0) flag[0] = isbf_l;
  }
  int stride = gridDim.x * blockDim.x;
  int g0 = blockIdx.x * blockDim.x + threadIdx.x;
  for (int i = g0; i < N; i += stride) {
    int b = bidx[i];
    if ((unsigned)b >= (unsigned)B) continue;
    if (i == 0 || bidx[i - 1] != b) rs[b] = i;
    if (i == N - 1 || bidx[i + 1] != b) ln[b] = pidx[i] + 1;
  }
  for (int i = g0; i < w1n; i += stride) {
    int o = i / 192, k = i - o * 192;          // W1[o][k], o<128, k<192
    int ct = o >> 4, n = o & 15;
    int ks = k >> 5, rem = k & 31;
    int q = rem >> 3, j = rem & 7;
    int fi = ((ct * 6 + ks) * 64 + q * 16 + n) * 8 + j;
    w1b[fi] = __float2bfloat16(ld1(W1, i, isbf_l));
  }
  // ---- fused stat: x_stat_out = leaky(bn2(x_stat @ W2^T + b2)) ----
  __shared__ float xs[64];
  if (threadIdx.x < 64 && blockIdx.x < B)
    xs[threadIdx.x] = ld1(xstat, blockIdx.x * 64 + threadIdx.x, isbf_l);
  __syncthreads();
  if (threadIdx.x < 64 && blockIdx.x < B) {
    const int o = threadIdx.x, bb = blockIdx.x;
    float acc = ld1(b2, o, isbf_l);
#pragma unroll 8
    for (int j = 0; j < 64; ++j) acc += xs[j] * ld1(W2, o * 64 + j, isbf_l);
    float k1 = ld1(g2, o, isbf_l) * rsqrtf(ld1(vr2, o, isbf_l) + EPS);
    float k0 = ld1(be2, o, isbf_l) - ld1(mn2, o, isbf_l) * k1;
    float v = acc * k1 + k0;
    v = (v >= 0.f) ? v : NSLOPE * v;
    st1(out, (size_t)(obase + bb * 64 + o), isbf_l, v);
  }
}

// ---------------------------------------------------------------------------
// Kf: flag-aware zero fill of x_out (fallback when ws too small)
// ---------------------------------------------------------------------------
__global__ void zfill_kernel(void* out, const int* __restrict__ flag, long long n) {
  const int isbf = flag[0];
  long long i = (long long)blockIdx.x * blockDim.x + threadIdx.x;
  long long stride = (long long)gridDim.x * blockDim.x;
  for (; i < n; i += stride) st1(out, (size_t)i, isbf, 0.f);
}

// ---------------------------------------------------------------------------
// Kta: RE-TILE temp_attn into bf16 tiles matching attn's per-wave per-chunk
// fragment: tb[b][tg=t/16][ci=s/64] is a 16x64 tile (2 KB contiguous).
// THEORY (r2..r9): attn is DRAM-page-bound on ta (128-256 B per 4 KB-strided
// row -> ~650 GB/s ceiling). This pass reads ta row-streaming (coalesced)
// and gives attn 2 KB-contiguous wave loads: span 256 B -> 2 KB, bytes /2.
// Rows t>=len are left unwritten: attn reads them as garbage but their MFMA
// output rows are never stored (rows are independent in D=A*B+C).
// ---------------------------------------------------------------------------
__global__ __launch_bounds__(256) void ta2b_kernel(
    const void* __restrict__ ta, const int* __restrict__ ln_arr,
    const int* __restrict__ flag, unsigned short* __restrict__ tb, int T) {
  const int isbf = flag[0];
  const int b = blockIdx.y, tg = blockIdx.x;   // tg: 16-row group (0..T/16-1)
  const int t0 = tg * 16;
  const int len = ln_arr[b];
  if (t0 >= len) return;
  const int c64 = ((len + 63) >> 6) << 6;      // cols attn will touch
  const int nr = min(16, len - t0);
  const int c = threadIdx.x * 4;               // 256 thr x 4 cols = 1024
  if (c >= c64) return;
  const int ci = c >> 6, sc = c & 63;
  unsigned short* dst = tb + (((size_t)(b * 64 + tg) * 16 + ci) << 10) + sc;
  for (int r = 0; r < nr; ++r) {
    const size_t src = ((size_t)b * T + (t0 + r)) * (size_t)T + c;
    ushort4 o;
    if (isbf) {
      o = *(const ushort4*)((const unsigned short*)ta + src);
    } else {
      float4 f = *(const float4*)((const float*)ta + src);
      o.x = (unsigned short)f2bs(f.x);
      o.y = (unsigned short)f2bs(f.y);
      o.z = (unsigned short)f2bs(f.z);
      o.w = (unsigned short)f2bs(f.w);
    }
    *(ushort4*)(dst + r * 64) = o;
  }
}

// ---------------------------------------------------------------------------
// K1: h = leaky(bn1(concat(x_temp, x_stat[bidx]) @ W1^T + b1))  via MFMA.
// ---------------------------------------------------------------------------
__global__ __launch_bounds__(256) void h_mfma_kernel(
    const void* __restrict__ xt, const void* __restrict__ xsg,
    const int* __restrict__ bidx, const bf16* __restrict__ w1b,
    const void* __restrict__ b1,
    const void* __restrict__ g1, const void* __restrict__ be1,
    const void* __restrict__ mn1, const void* __restrict__ vr1,
    const int* __restrict__ flag, bf16* __restrict__ hout, int N) {
  const int isbf = flag[0];
  const int tid = threadIdx.x, lane = tid & 63, wv = tid >> 6;
  const int m16 = lane & 15, quad = lane >> 4;
  const int row0 = blockIdx.x * 64 + wv * 16;
  const int m = row0 + m16;
  const int mc = (m < N) ? m : (N - 1);
  const int bi = bidx[mc];

  short8 af[6];
  if (isbf) {
    const bf16* xr = (const bf16*)xt + (size_t)mc * 128 + quad * 8;
#pragma unroll
    for (int ks = 0; ks < 4; ++ks) af[ks] = *(const short8*)(xr + ks * 32);
    const bf16* sr = (const bf16*)xsg + (size_t)bi * 64 + quad * 8;
    af[4] = *(const short8*)sr;
    af[5] = *(const short8*)(sr + 32);
  } else {
    const float* xr = (const float*)xt + (size_t)mc * 128 + quad * 8;
#pragma unroll
    for (int ks = 0; ks < 4; ++ks) af[ks] = pack8f(xr + ks * 32);
    const float* sr = (const float*)xsg + (size_t)bi * 64 + quad * 8;
    af[4] = pack8f(sr);
    af[5] = pack8f(sr + 32);
  }

  f32x4 acc[8];
#pragma unroll
  for (int ct = 0; ct < 8; ++ct) acc[ct] = (f32x4){0.f, 0.f, 0.f, 0.f};

  const short8* wf = (const short8*)w1b;   // fragment-ordered (see meta)
#pragma unroll
  for (int ks = 0; ks < 6; ++ks) {
#pragma unroll
    for (int ct = 0; ct < 8; ++ct) {
      short8 bfrag = wf[(ct * 6 + ks) * 64 + lane];
      acc[ct] = __builtin_amdgcn_mfma_f32_16x16x32_bf16(af[ks], bfrag, acc[ct], 0, 0, 0);
    }
  }

#pragma unroll
  for (int ct = 0; ct < 8; ++ct) {
    const int o = ct * 16 + m16;
    float k1 = ld1(g1, o, isbf) * rsqrtf(ld1(vr1, o, isbf) + EPS);
    float k0 = ld1(be1, o, isbf) - ld1(mn1, o, isbf) * k1;
    float bias = ld1(b1, o, isbf);
#pragma unroll
    for (int r = 0; r < 4; ++r) {
      int mr = row0 + quad * 4 + r;
      if (mr < N) {
        float v = (acc[ct][r] + bias) * k1 + k0;
        v = (v >= 0.f) ? v : NSLOPE * v;
        hout[(size_t)mr * 128 + o] = __float2bfloat16(v);
      }
    }
  }
}

// ---------------------------------------------------------------------------
// K3: fused online-softmax MFMA attention (r2 single-pass structure — best
// verified: 4 waves x 16 q-rows, one barrier/chunk, vT stride-72 dbuf).
// NEW: when useconv, ta is read from the tiled bf16 buffer tb — each wave's
// per-chunk fragment is TWO 1 KB wave-contiguous loads (vs 16 rows x 256 B
// at 4 KB stride). This is the decisive test of the DRAM-page-efficiency
// theory: bytes /2 AND span x8 with zero other changes.
// ---------------------------------------------------------------------------
__global__ __launch_bounds__(256, 2) void attn_mfma_kernel(
    const void* __restrict__ ta, const unsigned short* __restrict__ tb,
    const bf16* __restrict__ h,
    const int* __restrict__ rs_arr, const int* __restrict__ ln_arr,
    const int* __restrict__ flag, void* __restrict__ xout, int T, int N,
    int useconv) {
  __shared__ __align__(16) unsigned short vT[2][128][72];
  __shared__ __align__(16) unsigned short Pw[4][16][72];

  const int b = blockIdx.y, t0 = blockIdx.x * 64;
  const int len = ln_arr[b];
  if (t0 >= len) return;
  const int isbf = flag[0];
  const int rs = rs_arr[b];
  const int tid = threadIdx.x;
  const int lane = tid & 63, wv = tid >> 6;
  const int m16 = lane & 15, quad = lane >> 4;
  const int t0w = t0 + wv * 16;

  short8 qf[4];
  {
    int qrow = rs + t0w + m16;
    if (qrow > N - 1) qrow = N - 1;
    const bf16* qp = h + (size_t)qrow * 128 + quad * 8;
#pragma unroll
    for (int ks = 0; ks < 4; ++ks) qf[ks] = *(const short8*)(qp + ks * 32);
  }

  const float scale = 0.08838834764831845f;
  const short8 zero8 = {0, 0, 0, 0, 0, 0, 0, 0};
  const uint4 zz = {0, 0, 0, 0};
  const size_t tarow = ((size_t)b * T + (t0w + m16)) * (size_t)T;
  // tiled-tb base for this wave's 16-row group (tg = t0w/16)
  const size_t tbbase = ((size_t)(b * 64 + (t0w >> 4)) * 16) << 10;
  const int tboff = m16 * 64 + quad * 8;
  const int c8base = wv * 32;

  f32x4 accp[8], acct[8];
#pragma unroll
  for (int ct = 0; ct < 8; ++ct) {
    accp[ct] = (f32x4){0.f, 0.f, 0.f, 0.f};
    acct[ct] = (f32x4){0.f, 0.f, 0.f, 0.f};
  }
  float mrun[4], lrun[4];
#pragma unroll
  for (int r = 0; r < 4; ++r) { mrun[r] = -INFINITY; lrun[r] = 0.f; }

  {
    int srow = lane;
    bool v = srow < len;
    const bf16* src = h + (size_t)(rs + (v ? srow : 0)) * 128;
#pragma unroll
    for (int it = 0; it < 4; ++it) {
      int c8 = c8base + it * 8;
      uint4 u = v ? *(const uint4*)(src + c8) : zz;
      const unsigned short* a = (const unsigned short*)&u;
#pragma unroll
      for (int j = 0; j < 8; ++j) vT[0][c8 + j][lane] = a[j];
    }
  }
  __syncthreads();

  const int nchunk = (len + 63) >> 6;
  for (int ci = 0; ci < nchunk; ++ci) {
    const int s0 = ci << 6;
    const int p = ci & 1;
    const bool have_next = (ci + 1 < nchunk);

    uint4 su0 = zz, su1 = zz, su2 = zz, su3 = zz;
    if (have_next) {
      int srow = s0 + 64 + lane;
      bool v = srow < len;
      const bf16* src = h + (size_t)(rs + (v ? srow : 0)) * 128;
      if (v) {
        su0 = *(const uint4*)(src + c8base);
        su1 = *(const uint4*)(src + c8base + 8);
        su2 = *(const uint4*)(src + c8base + 16);
        su3 = *(const uint4*)(src + c8base + 24);
      }
    }

    // ---- temp_attn A-frags: tiled-tb path (2 KB-contiguous per wave) ----
    short8 taf0, taf1;
    if (useconv) {
      const unsigned short* tp = tb + tbbase + ((size_t)ci << 10) + tboff;
      taf0 = *(const short8*)tp;
      taf1 = *(const short8*)(tp + 32);
    } else if (isbf) {
      const bf16* tp = (const bf16*)ta + tarow + s0 + quad * 8;
      taf0 = *(const short8*)tp;
      taf1 = *(const short8*)(tp + 32);
    } else {
      const float* tp = (const float*)ta + tarow + s0 + quad * 8;
      taf0 = pack8f(tp);
      taf1 = pack8f(tp + 32);
    }

    f32x4 sa[4];
    bool sval[4];
#pragma unroll
    for (int st = 0; st < 4; ++st) {
      int srow = s0 + st * 16 + m16;
      bool v = srow < len;
      sval[st] = v;
      const bf16* kp = h + (size_t)(rs + (v ? srow : 0)) * 128 + quad * 8;
      f32x4 a0 = (f32x4){0.f, 0.f, 0.f, 0.f};
#pragma unroll
      for (int ks = 0; ks < 4; ++ks) {
        short8 kf = v ? *(const short8*)(kp + ks * 32) : zero8;
        a0 = __builtin_amdgcn_mfma_f32_16x16x32_bf16(qf[ks], kf, a0, 0, 0, 0);
      }
      sa[st] = a0;
    }

    float cm[4];
#pragma unroll
    for (int r = 0; r < 4; ++r) cm[r] = -INFINITY;
#pragma unroll
    for (int st = 0; st < 4; ++st) {
#pragma unroll
      for (int r = 0; r < 4; ++r)
        cm[r] = fmaxf(cm[r], sval[st] ? sa[st][r] * scale : -INFINITY);
    }
#pragma unroll
    for (int off = 1; off <= 8; off <<= 1) {
#pragma unroll
      for (int r = 0; r < 4; ++r) cm[r] = fmaxf(cm[r], __shfl_xor(cm[r], off, 64));
    }
    float al[4], csum[4];
#pragma unroll
    for (int r = 0; r < 4; ++r) {
      float mnew = fmaxf(mrun[r], cm[r]);
      al[r] = __expf(mrun[r] - mnew);
      mrun[r] = mnew;
      csum[r] = 0.f;
    }
#pragma unroll
    for (int st = 0; st < 4; ++st) {
#pragma unroll
      for (int r = 0; r < 4; ++r) {
        float pv = sval[st] ? __expf(sa[st][r] * scale - mrun[r]) : 0.f;
        csum[r] += pv;
        Pw[wv][quad * 4 + r][st * 16 + m16] = (unsigned short)f2bs(pv);
      }
    }
#pragma unroll
    for (int off = 1; off <= 8; off <<= 1) {
#pragma unroll
      for (int r = 0; r < 4; ++r) csum[r] += __shfl_xor(csum[r], off, 64);
    }
#pragma unroll
    for (int r = 0; r < 4; ++r) lrun[r] = lrun[r] * al[r] + csum[r];

#pragma unroll
    for (int ct = 0; ct < 8; ++ct) {
#pragma unroll
      for (int r = 0; r < 4; ++r) accp[ct][r] *= al[r];
    }

#pragma unroll
    for (int ks = 0; ks < 2; ++ks) {
      short8 pf = *(const short8*)&Pw[wv][m16][ks * 32 + quad * 8];
      short8 tf = ks ? taf1 : taf0;
#pragma unroll
      for (int ct = 0; ct < 8; ++ct) {
        short8 bfv = *(const short8*)&vT[p][ct * 16 + m16][ks * 32 + quad * 8];
        accp[ct] = __builtin_amdgcn_mfma_f32_16x16x32_bf16(pf, bfv, accp[ct], 0, 0, 0);
        acct[ct] = __builtin_amdgcn_mfma_f32_16x16x32_bf16(tf, bfv, acct[ct], 0, 0, 0);
      }
    }

    if (have_next) {
      const unsigned short* a0 = (const unsigned short*)&su0;
      const unsigned short* a1 = (const unsigned short*)&su1;
      const unsigned short* a2 = (const unsigned short*)&su2;
      const unsigned short* a3 = (const unsigned short*)&su3;
#pragma unroll
      for (int j = 0; j < 8; ++j) {
        vT[p ^ 1][c8base + j][lane]      = a0[j];
        vT[p ^ 1][c8base + 8 + j][lane]  = a1[j];
        vT[p ^ 1][c8base + 16 + j][lane] = a2[j];
        vT[p ^ 1][c8base + 24 + j][lane] = a3[j];
      }
    }
    __syncthreads();
  }

  const int nr = len - t0w;
#pragma unroll
  for (int r = 0; r < 4; ++r) {
    int t = quad * 4 + r;
    if (t < nr) {
      float m_r = mrun[r], l_r = lrun[r];
      float m_f = (len < T) ? fmaxf(m_r, 0.f) : m_r;
      float corr = __expf(m_r - m_f);
      float l_f = l_r * corr + (float)(T - len) * __expf(-m_f);
      float os = corr / l_f;
      size_t ob = (size_t)(rs + t0w + t) * 128;
#pragma unroll
      for (int ct = 0; ct < 8; ++ct)
        st1(xout, ob + ct * 16 + m16, isbf, accp[ct][r] * os + acct[ct][r]);
    }
  }
}

// ---------------------------------------------------------------------------
extern "C" void kernel_launch(void* const* d_in, const int* in_sizes, int n_in,
                              void* d_out, int out_size, void* d_ws, size_t ws_size,
                              hipStream_t stream) {
  const void* x_temp    = d_in[0];
  const void* x_stat    = d_in[1];
  const void* temp_attn = d_in[2];
  const int N = in_sizes[0] / 128;      // 23450
  const int B = in_sizes[1] / 64;       // 32
  long long tt = (long long)in_sizes[2] / B;
  int T = 1; while ((long long)(T + 1) * (T + 1) <= tt) ++T;  // isqrt -> 1024
  const int TT = (T + 63) >> 6;         // q-tiles per batch (16)

  int p = 3;
  while (p < n_in && in_sizes[p] != N) ++p;
  const int* batch_idx = (const int*)d_in[p++];
  const int* pos_idx   = (const int*)d_in[p++];
  const void* W1 = d_in[p++];
  const void* b1 = d_in[p++];
  const void* g1 = d_in[p++];
  const void* be1= d_in[p++];
  const void* mn1= d_in[p++];
  const void* vr1= d_in[p++];
  const void* W2 = d_in[p++];
  const void* b2 = d_in[p++];
  const void* g2 = d_in[p++];
  const void* be2= d_in[p++];
  const void* mn2= d_in[p++];
  const void* vr2= d_in[p++];

  int*  meta = (int*)d_ws;
  int*  rs   = meta;
  int*  lnp  = meta + B;
  int*  flag = meta + 2 * B;
  size_t off = 1024;
  bf16* h    = (bf16*)((char*)d_ws + off);  off += (size_t)N * 128 * 2;
  const int w1n = 128 * 192;
  bf16* w1b  = (bf16*)((char*)d_ws + off);  off += (size_t)w1n * 2;
  off = (off + 255) & ~(size_t)255;
  size_t need_min = off;
  // tiled ta buffer: B x (T/16 groups) x (T/64 chunks) x 16x64 bf16 tiles
  unsigned short* tb = (unsigned short*)((char*)d_ws + off);
  off += (size_t)B * (T / 16) * (T / 64) * 1024 * 2;   // 64 MB at T=1024
  size_t need_tb = off;
  int useconv = (ws_size >= need_tb) ? 1 : 0;

  long long obase = (long long)N * 128;

  meta_kernel<<<90, 256, 0, stream>>>(x_temp, batch_idx, pos_idx, N, B, rs, lnp,
                                      flag, W1, w1b, w1n,
                                      x_stat, W2, b2, g2, be2, mn2, vr2,
                                      d_out, obase);
  if (ws_size >= need_min) {
    h_mfma_kernel<<<(N + 63) / 64, 256, 0, stream>>>(x_temp, x_stat, batch_idx,
                                                     w1b, b1, g1, be1, mn1, vr1,
                                                     flag, h, N);
    if (useconv) {
      ta2b_kernel<<<dim3(T / 16, B), 256, 0, stream>>>(temp_attn, lnp, flag,
                                                       tb, T);
    }
    attn_mfma_kernel<<<dim3(TT, B), 256, 0, stream>>>(
        temp_attn, tb, h, rs, lnp, flag, d_out, T, N, useconv);
  } else {
    zfill_kernel<<<512, 256, 0, stream>>>(d_out, flag, obase);
  }
}